// Round 4
// baseline (385.042 us; speedup 1.0000x reference)
//
#include <hip/hip_runtime.h>
#include <hip/hip_bf16.h>

#define NN 16384
#define DD 256

typedef unsigned short u16;
typedef unsigned int u32;
typedef __attribute__((ext_vector_type(8))) __bf16 bf16x8;
typedef __attribute__((ext_vector_type(4))) float f32x4;

// ---------- helpers ----------
static __device__ __forceinline__ u16 f2bf(float f) {
    u32 u = __float_as_uint(f);
    u32 r = (u + 0x7fffu + ((u >> 16) & 1u)) >> 16;   // RNE
    return (u16)r;
}

// ---------- kernel 1: convert to bf16 (image scaled by log2(e)), zero sums ----------
__global__ void prep_kernel(const float* __restrict__ img, const float* __restrict__ txt,
                            u16* __restrict__ Abf, u16* __restrict__ Bbf,
                            float* __restrict__ zbuf /* s_row..s_col */, float* __restrict__ out) {
    int gid = blockIdx.x * 256 + threadIdx.x;          // 0 .. 1048575  (N*D/4)
    float4 va = ((const float4*)img)[gid];
    float4 vb = ((const float4*)txt)[gid];
    ushort4 ua, ub;
    const float S = 1.44269504088896f;                  // log2(e)
    ua.x = f2bf(va.x * S); ua.y = f2bf(va.y * S); ua.z = f2bf(va.z * S); ua.w = f2bf(va.w * S);
    ub.x = f2bf(vb.x);     ub.y = f2bf(vb.y);     ub.z = f2bf(vb.z);     ub.w = f2bf(vb.w);
    ((ushort4*)Abf)[gid] = ua;
    ((ushort4*)Bbf)[gid] = ub;
    if (gid < 32768) zbuf[gid] = 0.0f;
    if (gid == 0) out[0] = 0.0f;
}

// ---------- kernel 2: fused GEMM + exp2 + row/col sum + diag ----------
// NO LDS, NO BARRIERS. Grid: 1024 blocks = 128 bi x 8 jg. Block: 128-row tile,
// 2x2 waves (wave = 64 rows x 64 cols), persistent sweep over 16 column tiles.
// A operand lives in registers (Areg[4][8], 128 VGPRs), loaded once.
// B fragments are loaded straight global->VGPR (16 B/lane, 4-lane line-coalesced,
// L1/L2-hot: each B panel re-read by 128 blocks, wr-pairs dedup in L1), register
// double-buffered one MFMA-step ahead -> compiler emits fine-grained vmcnt(N)
// pipelining with no barrier drain anywhere in the K-loop.
// Row sums accumulate in per-lane registers across all 16 tiles (one butterfly +
// one atomic per lane per block); col sums: 2 shuffles + 1 atomic per lane per tile.
__global__ __launch_bounds__(256, 2) void gemm_lse_kernel(
        const u16* __restrict__ Abf, const u16* __restrict__ Bbf,
        float* __restrict__ s_row, float* __restrict__ s_col,
        float* __restrict__ diag) {
    const int t = threadIdx.x;
    const int lane = t & 63;
    const int w = t >> 6;
    const int wr = w >> 1, wc = w & 1;
    const int q = lane >> 4, m = lane & 15;
    const int bi = blockIdx.x & 127;
    const int jg = blockIdx.x >> 7;
    const int row0 = bi << 7;

    // ---- A -> registers: Areg[rb][s] = A[row0+wr*64+rb*16+m][s*32+q*8 .. +8]
    bf16x8 Areg[4][8];
    #pragma unroll
    for (int rb = 0; rb < 4; ++rb) {
        const u16* ap = Abf + (size_t)(row0 + (wr << 6) + (rb << 4) + m) * DD + (q << 3);
        #pragma unroll
        for (int s = 0; s < 8; ++s)
            Areg[rb][s] = *(const bf16x8*)(ap + (s << 5));
    }

    const f32x4 fzero = {0.f, 0.f, 0.f, 0.f};
    f32x4 acc[4][4];
    #pragma unroll
    for (int a = 0; a < 4; ++a)
        #pragma unroll
        for (int b = 0; b < 4; ++b) acc[a][b] = fzero;
    f32x4 rp[4] = {fzero, fzero, fzero, fzero};   // row partials, whole block

    // lane's B base: col component (wc*64 + m), k component q*8
    const u16* bbase = Bbf + (size_t)((wc << 6) + m) * DD + (q << 3);

    bf16x8 bq[2][4];
    {   // preload jt=0, s=0
        const u16* bp = bbase + (size_t)((jg << 4) << 7) * DD;
        #pragma unroll
        for (int cb = 0; cb < 4; ++cb)
            bq[0][cb] = *(const bf16x8*)(bp + (size_t)(cb << 4) * DD);
    }

    #pragma unroll 1
    for (int jt = 0; jt < 16; ++jt) {
        const int col0 = ((jg << 4) + jt) << 7;
        const u16* bp = bbase + (size_t)col0 * DD;
        #pragma unroll
        for (int s = 0; s < 8; ++s) {
            // prefetch next step's 4 fragments (next tile's s=0 when s==7)
            {
                const int ns = (s + 1) & 7;
                const u16* np = (s == 7)
                    ? bbase + (size_t)(((jg << 4) + (jt < 15 ? jt + 1 : 15)) << 7) * DD
                    : bp;
                #pragma unroll
                for (int cb = 0; cb < 4; ++cb)
                    bq[(s + 1) & 1][cb] = *(const bf16x8*)(np + (size_t)(cb << 4) * DD + (ns << 5));
            }
            #pragma unroll
            for (int rb = 0; rb < 4; ++rb)
                #pragma unroll
                for (int cb = 0; cb < 4; ++cb)
                    acc[rb][cb] = __builtin_amdgcn_mfma_f32_16x16x32_bf16(
                        Areg[rb][s], bq[s & 1][cb], acc[rb][cb], 0, 0, 0);
        }

        // ---- per-tile epilogue (registers + global atomics only) ----
        // diag (pre-exp, log2-scaled): D layout col=m, row=q*4+r
        if (bi == ((jg << 4) + jt) && wr == wc) {
            #pragma unroll
            for (int rb = 0; rb < 4; ++rb)
                #pragma unroll
                for (int r = 0; r < 4; ++r)
                    if (m == ((q << 2) | r))
                        diag[row0 + (wr << 6) + (rb << 4) + m] = acc[rb][rb][r];
        }
        // exp2(l' - 144) in place
        #pragma unroll
        for (int rb = 0; rb < 4; ++rb)
            #pragma unroll
            for (int cb = 0; cb < 4; ++cb)
                #pragma unroll
                for (int r = 0; r < 4; ++r)
                    acc[rb][cb][r] = __builtin_amdgcn_exp2f(acc[rb][cb][r] - 144.0f);

        // row partials: no shuffles, pure VALU; reduced once at block end
        #pragma unroll
        for (int rb = 0; rb < 4; ++rb)
            rp[rb] += (acc[rb][0] + acc[rb][1]) + (acc[rb][2] + acc[rb][3]);

        // col partials: in-lane rb/r adds + 2 cross-quad shuffles; lane keeps cb==q
        float cpart = 0.0f;
        #pragma unroll
        for (int cb = 0; cb < 4; ++cb) {
            float v = 0.0f;
            #pragma unroll
            for (int rb = 0; rb < 4; ++rb)
                v += (acc[rb][cb][0] + acc[rb][cb][1]) + (acc[rb][cb][2] + acc[rb][cb][3]);
            v += __shfl_xor(v, 16, 64);
            v += __shfl_xor(v, 32, 64);
            if (q == cb) cpart = v;
        }
        atomicAdd(&s_col[col0 + (wc << 6) + (q << 4) + m], cpart);

        // re-zero accumulators for next tile
        #pragma unroll
        for (int a = 0; a < 4; ++a)
            #pragma unroll
            for (int b = 0; b < 4; ++b) acc[a][b] = fzero;
    }

    // ---- block-end row reduction: rp[rb][r] is row (row0+wr*64+rb*16+q*4+r),
    // distributed over the 16 m-lanes of quad q. Butterfly over m, lane m==rb*4+r writes.
    float rout = 0.0f;
    #pragma unroll
    for (int rb = 0; rb < 4; ++rb)
        #pragma unroll
        for (int r = 0; r < 4; ++r) {
            float v = rp[rb][r];
            v += __shfl_xor(v, 1, 16);
            v += __shfl_xor(v, 2, 16);
            v += __shfl_xor(v, 4, 16);
            v += __shfl_xor(v, 8, 16);
            if (m == ((rb << 2) | r)) rout = v;
        }
    atomicAdd(&s_row[row0 + (wr << 6) + ((m >> 2) << 4) + (q << 2) + (m & 3)], rout);
}

// ---------- kernel 3: final reduce (64 blocks, 256 rows each) ----------
__global__ void final_kernel(const float* __restrict__ s_row, const float* __restrict__ s_col,
                             const float* __restrict__ diag, float* __restrict__ out) {
    __shared__ double red[256];
    int t = threadIdx.x;
    int i = blockIdx.x * 256 + t;
    double p = 0.5 * (double)(log2f(s_row[i]) + log2f(s_col[i])) + 144.0 - (double)diag[i];
    red[t] = p;
    __syncthreads();
    for (int s = 128; s > 0; s >>= 1) {
        if (t < s) red[t] += red[t + s];
        __syncthreads();
    }
    if (t == 0) atomicAdd(out, (float)(red[0] * 0.6931471805599453 / (double)NN));
}

// ---------- launch ----------
extern "C" void kernel_launch(void* const* d_in, const int* in_sizes, int n_in,
                              void* d_out, int out_size, void* d_ws, size_t ws_size,
                              hipStream_t stream) {
    const float* img = (const float*)d_in[0];
    const float* txt = (const float*)d_in[1];
    char* ws = (char*)d_ws;
    u16*   Abf   = (u16*)ws;                               // 8 MB
    u16*   Bbf   = (u16*)(ws + 8388608);                   // 8 MB
    float* s_row = (float*)(ws + 16777216);                // 64 KB
    float* s_col = (float*)(ws + 16777216 + 65536);        // 64 KB
    float* diag  = (float*)(ws + 16777216 + 131072);       // 64 KB
    float* out   = (float*)d_out;

    prep_kernel<<<4096, 256, 0, stream>>>(img, txt, Abf, Bbf, s_row, out);
    gemm_lse_kernel<<<1024, 256, 0, stream>>>(Abf, Bbf, s_row, s_col, diag);
    final_kernel<<<64, 256, 0, stream>>>(s_row, s_col, diag, out);
}

// Round 5
// 262.183 us; speedup vs baseline: 1.4686x; 1.4686x over previous
//
#include <hip/hip_runtime.h>
#include <hip/hip_bf16.h>

#define NN 16384
#define DD 256

typedef unsigned short u16;
typedef unsigned int u32;
typedef __attribute__((ext_vector_type(8))) __bf16 bf16x8;
typedef __attribute__((ext_vector_type(4))) float f32x4;

// ---------- helpers ----------
static __device__ __forceinline__ u16 f2bf(float f) {
    u32 u = __float_as_uint(f);
    u32 r = (u + 0x7fffu + ((u >> 16) & 1u)) >> 16;   // RNE
    return (u16)r;
}

// async global->LDS, 16B per lane; LDS dest = wave-uniform base + lane*16
static __device__ __forceinline__ void gload16(const u16* g, u16* l) {
    __builtin_amdgcn_global_load_lds(
        (const __attribute__((address_space(1))) void*)g,
        (__attribute__((address_space(3))) void*)l,
        16, 0, 0);
}

// ---------- kernel 1: convert to bf16 (image scaled by log2(e)), zero sums ----------
__global__ void prep_kernel(const float* __restrict__ img, const float* __restrict__ txt,
                            u16* __restrict__ Abf, u16* __restrict__ Bbf,
                            float* __restrict__ zbuf /* s_row..s_col */, float* __restrict__ out) {
    int gid = blockIdx.x * 256 + threadIdx.x;          // 0 .. 1048575  (N*D/4)
    float4 va = ((const float4*)img)[gid];
    float4 vb = ((const float4*)txt)[gid];
    ushort4 ua, ub;
    const float S = 1.44269504088896f;                  // log2(e)
    ua.x = f2bf(va.x * S); ua.y = f2bf(va.y * S); ua.z = f2bf(va.z * S); ua.w = f2bf(va.w * S);
    ub.x = f2bf(vb.x);     ub.y = f2bf(vb.y);     ub.z = f2bf(vb.z);     ub.w = f2bf(vb.w);
    ((ushort4*)Abf)[gid] = ua;
    ((ushort4*)Bbf)[gid] = ub;
    if (gid < 32768) zbuf[gid] = 0.0f;
    if (gid == 0) out[0] = 0.0f;
}

// ---------- kernel 2: fused GEMM + exp2 + row/col sum + diag ----------
// Grid: 1024 blocks = 128 bi x 8 jg. Block: 128-row panel; A (128x256, 64 KB)
// staged into LDS ONCE via global_load_lds (XOR-swizzled, 0-conflict), then a
// sweep over 16 column tiles; per K-chunk only B (128x64, 16 KB) is staged.
// 64 chunks/block amortize the prologue; staging per chunk is half of R2's.
// LDS 80 KB -> 2 blocks/CU. Row partials in registers across all tiles
// (one butterfly+atomic per block); col sums 2 shuffles + 1 atomic per tile;
// acc re-zero folded into first MFMA (C=0).
__global__ __launch_bounds__(256, 2) void gemm_lse_kernel(
        const u16* __restrict__ Abf, const u16* __restrict__ Bbf,
        float* __restrict__ s_row, float* __restrict__ s_col,
        float* __restrict__ diag) {
    __shared__ u16 sA[128 * 256];   // row stride 512 B = 32 chunks of 16 B
    __shared__ u16 sB[128 * 64];    // row stride 128 B = 8 chunks of 16 B

    const int t = threadIdx.x;
    const int lane = t & 63;
    const int w = t >> 6;
    const int wr = w >> 1, wc = w & 1;
    const int q = lane >> 4, m = lane & 15;
    const int bi = blockIdx.x & 127;
    const int jg = blockIdx.x >> 7;
    const int row0 = bi << 7;

    // ---- stage A panel once. Round R: 256 threads x 16 B = 8 rows.
    // lane l of wave w -> row R*8 + w*2 + (l>>5), slot l&31; LDS(row,slot)
    // holds global chunk slot ^ (row & 7).
    {
        const int arow = (w << 1) + (lane >> 5);       // row within round, 0..7
        const int slot = lane & 31;
        const int gch = slot ^ arow;                   // row & 7 == arow
        #pragma unroll
        for (int R = 0; R < 16; ++R) {
            gload16(Abf + (size_t)(row0 + (R << 3) + arow) * DD + (gch << 3),
                    &sA[((R << 3) + (w << 1)) << 8]);
        }
    }

    // B staging decomposition: wave w covers tile-rows [w*32, w*32+32)
    const int srow = w << 5;
    const int lr = lane >> 3;       // row within 8-row group
    const int cc8 = lane & 7;       // LDS chunk within row
    const int gbch = cc8 ^ lr;      // swizzled global chunk (row & 7 == lr)

    const f32x4 fzero = {0.f, 0.f, 0.f, 0.f};
    f32x4 acc[4][4];
    f32x4 rp[4] = {fzero, fzero, fzero, fzero};   // row partials, whole block

    #pragma unroll 1
    for (int jt = 0; jt < 16; ++jt) {
        const int col0 = ((jg << 4) + jt) << 7;
        #pragma unroll
        for (int kc = 0; kc < 4; ++kc) {
            const int kb = kc << 6;
            __syncthreads();   // prior compute done with sB (and A drained, 1st iter)
            {
                const size_t pbase = (size_t)(col0 + srow + lr) * DD + kb + (gbch << 3);
                #pragma unroll
                for (int jj = 0; jj < 4; ++jj)
                    gload16(Bbf + pbase + (size_t)(jj << 3) * DD,
                            &sB[(srow + (jj << 3)) << 6]);
            }
            __syncthreads();   // drains vmcnt -> sB chunk ready
            #pragma unroll
            for (int s = 0; s < 2; ++s) {
                const int k8 = (s << 2) + q;           // B chunk in row, 0..7
                const int ga = (kc << 3) + k8;         // A chunk in row, 0..31
                bf16x8 af[4], bfv[4];
                #pragma unroll
                for (int rb = 0; rb < 4; ++rb) {
                    const int rr = (wr << 6) + (rb << 4) + m;
                    af[rb]  = *(const bf16x8*)(&sA[(rr << 8) + ((ga ^ (m & 7)) << 3)]);
                    const int ccr = (wc << 6) + (rb << 4) + m;
                    bfv[rb] = *(const bf16x8*)(&sB[(ccr << 6) + ((k8 ^ (m & 7)) << 3)]);
                }
                if (kc == 0 && s == 0) {
                    #pragma unroll
                    for (int rb = 0; rb < 4; ++rb)
                        #pragma unroll
                        for (int cb = 0; cb < 4; ++cb)
                            acc[rb][cb] = __builtin_amdgcn_mfma_f32_16x16x32_bf16(
                                af[rb], bfv[cb], fzero, 0, 0, 0);
                } else {
                    #pragma unroll
                    for (int rb = 0; rb < 4; ++rb)
                        #pragma unroll
                        for (int cb = 0; cb < 4; ++cb)
                            acc[rb][cb] = __builtin_amdgcn_mfma_f32_16x16x32_bf16(
                                af[rb], bfv[cb], acc[rb][cb], 0, 0, 0);
                }
            }
        }

        // ---- per-tile epilogue (registers + global atomics only) ----
        // diag (pre-exp, log2-scaled): D layout col=m, row=q*4+r
        if (bi == ((jg << 4) + jt) && wr == wc) {
            #pragma unroll
            for (int rb = 0; rb < 4; ++rb)
                #pragma unroll
                for (int r = 0; r < 4; ++r)
                    if (m == ((q << 2) | r))
                        diag[row0 + (wr << 6) + (rb << 4) + m] = acc[rb][rb][r];
        }
        // exp2(l' - 144) in place
        #pragma unroll
        for (int rb = 0; rb < 4; ++rb)
            #pragma unroll
            for (int cb = 0; cb < 4; ++cb)
                #pragma unroll
                for (int r = 0; r < 4; ++r)
                    acc[rb][cb][r] = __builtin_amdgcn_exp2f(acc[rb][cb][r] - 144.0f);

        // row partials: pure VALU, reduced once at block end
        #pragma unroll
        for (int rb = 0; rb < 4; ++rb)
            rp[rb] += (acc[rb][0] + acc[rb][1]) + (acc[rb][2] + acc[rb][3]);

        // col partials: in-lane adds + 2 cross-quad shuffles; lane keeps cb==q
        float cpart = 0.0f;
        #pragma unroll
        for (int cb = 0; cb < 4; ++cb) {
            float v = 0.0f;
            #pragma unroll
            for (int rb = 0; rb < 4; ++rb)
                v += (acc[rb][cb][0] + acc[rb][cb][1]) + (acc[rb][cb][2] + acc[rb][cb][3]);
            v += __shfl_xor(v, 16, 64);
            v += __shfl_xor(v, 32, 64);
            if (q == cb) cpart = v;
        }
        atomicAdd(&s_col[col0 + (wc << 6) + (q << 4) + m], cpart);
    }

    // ---- block-end row reduction: rp[rb][r] is row (wr*64+rb*16+q*4+r),
    // distributed over the 16 m-lanes of quad q. Butterfly over m.
    float rout = 0.0f;
    #pragma unroll
    for (int rb = 0; rb < 4; ++rb)
        #pragma unroll
        for (int r = 0; r < 4; ++r) {
            float v = rp[rb][r];
            v += __shfl_xor(v, 1, 16);
            v += __shfl_xor(v, 2, 16);
            v += __shfl_xor(v, 4, 16);
            v += __shfl_xor(v, 8, 16);
            if (m == ((rb << 2) | r)) rout = v;
        }
    atomicAdd(&s_row[row0 + (wr << 6) + ((m >> 2) << 4) + (q << 2) + (m & 3)], rout);
}

// ---------- kernel 3: final reduce (64 blocks, 256 rows each) ----------
__global__ void final_kernel(const float* __restrict__ s_row, const float* __restrict__ s_col,
                             const float* __restrict__ diag, float* __restrict__ out) {
    __shared__ double red[256];
    int t = threadIdx.x;
    int i = blockIdx.x * 256 + t;
    double p = 0.5 * (double)(log2f(s_row[i]) + log2f(s_col[i])) + 144.0 - (double)diag[i];
    red[t] = p;
    __syncthreads();
    for (int s = 128; s > 0; s >>= 1) {
        if (t < s) red[t] += red[t + s];
        __syncthreads();
    }
    if (t == 0) atomicAdd(out, (float)(red[0] * 0.6931471805599453 / (double)NN));
}

// ---------- launch ----------
extern "C" void kernel_launch(void* const* d_in, const int* in_sizes, int n_in,
                              void* d_out, int out_size, void* d_ws, size_t ws_size,
                              hipStream_t stream) {
    const float* img = (const float*)d_in[0];
    const float* txt = (const float*)d_in[1];
    char* ws = (char*)d_ws;
    u16*   Abf   = (u16*)ws;                               // 8 MB
    u16*   Bbf   = (u16*)(ws + 8388608);                   // 8 MB
    float* s_row = (float*)(ws + 16777216);                // 64 KB
    float* s_col = (float*)(ws + 16777216 + 65536);        // 64 KB
    float* diag  = (float*)(ws + 16777216 + 131072);       // 64 KB
    float* out   = (float*)d_out;

    prep_kernel<<<4096, 256, 0, stream>>>(img, txt, Abf, Bbf, s_row, out);
    gemm_lse_kernel<<<1024, 256, 0, stream>>>(Abf, Bbf, s_row, s_col, diag);
    final_kernel<<<64, 256, 0, stream>>>(s_row, s_col, diag, out);
}